// Round 1
// baseline (814.796 us; speedup 1.0000x reference)
//
#include <hip/hip_runtime.h>

typedef __bf16 bf16x8 __attribute__((ext_vector_type(8)));
typedef float f32x4 __attribute__((ext_vector_type(4)));

#define N_TOK 8192
#define DMODEL 1024
#define NEXP 64
#define ESIZE 128

__device__ __forceinline__ unsigned short f2bf(float f) {
  unsigned int u = __builtin_bit_cast(unsigned int, f);
  u += 0x7FFFu + ((u >> 16) & 1u);
  return (unsigned short)(u >> 16);
}

__device__ __forceinline__ void atomAddF(float* p, float v) {
  __hip_atomic_fetch_add(p, v, __ATOMIC_RELAXED, __HIP_MEMORY_SCOPE_AGENT);
}

// K0: expert_sel [64][1024] -> selT [1024][64] fp32 (coalesced router reads)
__global__ void k_selT(const float* __restrict__ in, float* __restrict__ outT) {
  int id = blockIdx.x * 256 + threadIdx.x;  // 65536 total
  int e = id & 63, j = id >> 6;
  outT[id] = in[e * DMODEL + j];
}

// K1: x fp32 -> bf16 (vectorized, 8 elems/thread)
__global__ void k_castx(const float* __restrict__ in, unsigned short* __restrict__ out) {
  size_t i = (size_t)(blockIdx.x * 256 + threadIdx.x) * 8;
  float4 a = *reinterpret_cast<const float4*>(in + i);
  float4 b = *reinterpret_cast<const float4*>(in + i + 4);
  uint4 o;
  o.x = f2bf(a.x) | ((unsigned)f2bf(a.y) << 16);
  o.y = f2bf(a.z) | ((unsigned)f2bf(a.w) << 16);
  o.z = f2bf(b.x) | ((unsigned)f2bf(b.y) << 16);
  o.w = f2bf(b.z) | ((unsigned)f2bf(b.w) << 16);
  *reinterpret_cast<uint4*>(out + i) = o;
}

// K2: per-expert transpose+cast: in [B][R][C] f32 -> out [B][C][R] bf16
__global__ void k_transpose(const float* __restrict__ in, unsigned short* __restrict__ out,
                            int R, int C) {
  __shared__ float t[32][33];
  int b = blockIdx.y;
  int tilesC = C >> 5;
  int tr = blockIdx.x / tilesC, tc = blockIdx.x % tilesC;
  int lr = threadIdx.x >> 5, lc = threadIdx.x & 31;
  const float* ip = in + (size_t)b * R * C;
  unsigned short* op = out + (size_t)b * R * C;
#pragma unroll
  for (int p = 0; p < 4; ++p)
    t[p * 8 + lr][lc] = ip[(size_t)(tr * 32 + p * 8 + lr) * C + tc * 32 + lc];
  __syncthreads();
#pragma unroll
  for (int p = 0; p < 4; ++p)
    op[(size_t)(tc * 32 + p * 8 + lr) * R + tr * 32 + lc] = f2bf(t[lc][p * 8 + lr]);
}

// K3: router — logits in fp64 accumulation (top-k rank fidelity), wave-wide top-4.
// One wave handles 8 tokens; lane = expert index.
__global__ __launch_bounds__(256) void k_router(const float* __restrict__ x,
                                                const float* __restrict__ selT,
                                                int4* __restrict__ idx4,
                                                float4* __restrict__ g4) {
  int lane = threadIdx.x & 63;
  int wid = blockIdx.x * 4 + (threadIdx.x >> 6);
  int tok0 = wid * 8;
  double acc[8];
#pragma unroll
  for (int t = 0; t < 8; ++t) acc[t] = 0.0;
  for (int j = 0; j < DMODEL; ++j) {
    double s = (double)selT[j * 64 + lane];
#pragma unroll
    for (int t = 0; t < 8; ++t)
      acc[t] += (double)x[(size_t)(tok0 + t) * DMODEL + j] * s;
  }
#pragma unroll
  for (int t = 0; t < 8; ++t) {
    double v = acc[t];
    int bi[4];
    double bl[4];
#pragma unroll
    for (int h = 0; h < 4; ++h) {
      double mv = v;
      int mi = lane;
#pragma unroll
      for (int off = 32; off > 0; off >>= 1) {
        double ov = __shfl_xor(mv, off);
        int oi = __shfl_xor(mi, off);
        if (ov > mv || (ov == mv && oi < mi)) { mv = ov; mi = oi; }
      }
      bi[h] = mi;
      bl[h] = mv;
      if (lane == mi) v = -1.0e300;
    }
    if (lane == 0) {
      idx4[tok0 + t] = make_int4(bi[0], bi[1], bi[2], bi[3]);
      float4 g;
      g.x = 1.0f / (1.0f + __expf(-(float)bl[0]));
      g.y = 1.0f / (1.0f + __expf(-(float)bl[1]));
      g.z = 1.0f / (1.0f + __expf(-(float)bl[2]));
      g.w = 1.0f / (1.0f + __expf(-(float)bl[3]));
      g4[tok0 + t] = g;
    }
  }
}

// K4: deterministic bucketize — block e collects tokens selecting expert e, ascending order.
__global__ __launch_bounds__(256) void k_bucket(const int4* __restrict__ idx4,
                                                const float4* __restrict__ g4,
                                                int* __restrict__ btok,
                                                float* __restrict__ bgate,
                                                int* __restrict__ cnt) {
  int e = blockIdx.x;
  int tid = threadIdx.x, lane = tid & 63, wid = tid >> 6;
  __shared__ int wcnt[4];
  int base = 0;
  for (int chunk = 0; chunk < N_TOK; chunk += 256) {
    int n = chunk + tid;
    int4 I = idx4[n];
    float4 G = g4[n];
    int h = (I.x == e) ? 0 : (I.y == e) ? 1 : (I.z == e) ? 2 : (I.w == e) ? 3 : -1;
    unsigned long long b = __ballot(h >= 0);
    if (lane == 0) wcnt[wid] = (int)__popcll(b);
    __syncthreads();
    int wbase = base;
    for (int w = 0; w < wid; ++w) wbase += wcnt[w];
    if (h >= 0) {
      int pos = wbase + (int)__popcll(b & ((1ULL << lane) - 1ULL));
      btok[e * N_TOK + pos] = n;
      bgate[e * N_TOK + pos] = (h == 0) ? G.x : (h == 1) ? G.y : (h == 2) ? G.z : G.w;
    }
    base += wcnt[0] + wcnt[1] + wcnt[2] + wcnt[3];
    __syncthreads();
  }
  if (tid == 0) cnt[e] = base;
}

// K5: fused per-expert: H = relu(X Kt)*gate; out += (H V) via outT = Vt * Ht
// 64-token tile, 4 waves, 16x16x32 bf16 MFMA.
__global__ __launch_bounds__(256) void k_expert(const unsigned short* __restrict__ xbf,
                                                const unsigned short* __restrict__ kbf,
                                                const unsigned short* __restrict__ vbf,
                                                const int* __restrict__ btok,
                                                const float* __restrict__ bgate,
                                                const int* __restrict__ cnt,
                                                float* __restrict__ out) {
  int k = blockIdx.y, tile = blockIdx.x;
  int ck = cnt[k];
  if (tile * 64 >= ck) return;
  int tid = threadIdx.x, lane = tid & 63, w = tid >> 6;

  __shared__ alignas(16) unsigned short lA[64][40];    // tokens x 32d (pad->80B rows)
  __shared__ alignas(16) unsigned short lB[128][40];   // e x 32d  / v x 32e
  __shared__ alignas(16) unsigned short lS[64][136];   // scores tok x e
  __shared__ int sTok[64];
  __shared__ float sGate[64];

  if (tid < 64) {
    int i = tile * 64 + tid;
    bool valid = i < ck;
    sTok[tid] = valid ? btok[k * N_TOK + i] : 0;
    sGate[tid] = valid ? bgate[k * N_TOK + i] : 0.0f;
  }
  __syncthreads();

  int arow = tid >> 2, seg = tid & 3;
  const unsigned short* xrow = xbf + (size_t)sTok[arow] * DMODEL + seg * 8;
  const unsigned short* kb = kbf + (size_t)k * (ESIZE * DMODEL);
  const unsigned short* vb = vbf + (size_t)k * (DMODEL * ESIZE);
  const int col = lane & 15, grp = lane >> 4;
  const int kofs = grp * 8;

  // ---- GEMM1: H[tok][e] = X[tok][d] * keys[d][e]  (A=xbf row-major, B from kbf[e][d])
  f32x4 acc[8] = {};
  for (int kk = 0; kk < DMODEL; kk += 32) {
    *reinterpret_cast<int4*>(&lA[arow][seg * 8]) =
        *reinterpret_cast<const int4*>(xrow + kk);
    *reinterpret_cast<int4*>(&lB[arow][seg * 8]) =
        *reinterpret_cast<const int4*>(kb + (size_t)arow * DMODEL + kk + seg * 8);
    *reinterpret_cast<int4*>(&lB[64 + arow][seg * 8]) =
        *reinterpret_cast<const int4*>(kb + (size_t)(64 + arow) * DMODEL + kk + seg * 8);
    __syncthreads();
    bf16x8 a = *reinterpret_cast<const bf16x8*>(&lA[w * 16 + col][kofs]);
#pragma unroll
    for (int nf = 0; nf < 8; ++nf) {
      bf16x8 b = *reinterpret_cast<const bf16x8*>(&lB[nf * 16 + col][kofs]);
      acc[nf] = __builtin_amdgcn_mfma_f32_16x16x32_bf16(a, b, acc[nf], 0, 0, 0);
    }
    __syncthreads();
  }

  // relu * gate -> lS[tok][e] bf16
#pragma unroll
  for (int nf = 0; nf < 8; ++nf) {
    int e = nf * 16 + col;
#pragma unroll
    for (int r = 0; r < 4; ++r) {
      int row = w * 16 + grp * 4 + r;
      float s = acc[nf][r];
      s = s > 0.0f ? s * sGate[row] : 0.0f;
      lS[row][e] = f2bf(s);
    }
  }
  __syncthreads();

  // ---- GEMM2 (transposed): outT[v][tok] = Vt[v][e] * St[e][tok]
  for (int vc = 0; vc < 8; ++vc) {
    f32x4 acc2[8] = {};
    for (int ec = 0; ec < 4; ++ec) {
      *reinterpret_cast<int4*>(&lB[arow][seg * 8]) =
          *reinterpret_cast<const int4*>(vb + (size_t)(vc * 128 + arow) * ESIZE + ec * 32 + seg * 8);
      *reinterpret_cast<int4*>(&lB[64 + arow][seg * 8]) =
          *reinterpret_cast<const int4*>(vb + (size_t)(vc * 128 + 64 + arow) * ESIZE + ec * 32 + seg * 8);
      __syncthreads();
#pragma unroll
      for (int mf = 0; mf < 2; ++mf) {
        bf16x8 a = *reinterpret_cast<const bf16x8*>(&lB[w * 32 + mf * 16 + col][kofs]);
#pragma unroll
        for (int nf = 0; nf < 4; ++nf) {
          bf16x8 b = *reinterpret_cast<const bf16x8*>(&lS[nf * 16 + col][ec * 32 + kofs]);
          acc2[mf * 4 + nf] =
              __builtin_amdgcn_mfma_f32_16x16x32_bf16(a, b, acc2[mf * 4 + nf], 0, 0, 0);
        }
      }
      __syncthreads();
    }
    // scatter: D row = v-local = grp*4+r, col = token-local
#pragma unroll
    for (int mf = 0; mf < 2; ++mf) {
#pragma unroll
      for (int nf = 0; nf < 4; ++nf) {
        int tl = nf * 16 + col;
        if (tile * 64 + tl < ck) {
          float* op = out + (size_t)sTok[tl] * DMODEL + vc * 128 + w * 32 + mf * 16 + grp * 4;
#pragma unroll
          for (int r = 0; r < 4; ++r) atomAddF(op + r, acc2[mf * 4 + nf][r]);
        }
      }
    }
  }
}

extern "C" void kernel_launch(void* const* d_in, const int* in_sizes, int n_in,
                              void* d_out, int out_size, void* d_ws, size_t ws_size,
                              hipStream_t stream) {
  const float* x = (const float*)d_in[0];
  const float* esel = (const float*)d_in[1];
  const float* keys = (const float*)d_in[2];
  const float* values = (const float*)d_in[3];
  float* out = (float*)d_out;

  // workspace layout (~52.5 MiB total)
  char* p = (char*)d_ws;
  unsigned short* xbf = (unsigned short*)p; p += (size_t)N_TOK * DMODEL * 2;
  unsigned short* kbf = (unsigned short*)p; p += (size_t)NEXP * DMODEL * ESIZE * 2;
  unsigned short* vbf = (unsigned short*)p; p += (size_t)NEXP * DMODEL * ESIZE * 2;
  float* selT = (float*)p; p += (size_t)DMODEL * NEXP * 4;
  float4* g4 = (float4*)p; p += (size_t)N_TOK * 16;
  int4* idx4 = (int4*)p; p += (size_t)N_TOK * 16;
  int* btok = (int*)p; p += (size_t)NEXP * N_TOK * 4;
  float* bgate = (float*)p; p += (size_t)NEXP * N_TOK * 4;
  int* cnt = (int*)p; p += 256;
  (void)ws_size; (void)in_sizes; (void)n_in;

  hipMemsetAsync(d_out, 0, (size_t)out_size * 4, stream);
  k_selT<<<256, 256, 0, stream>>>(esel, selT);
  k_castx<<<(N_TOK * DMODEL / 8) / 256, 256, 0, stream>>>(x, xbf);
  k_transpose<<<dim3(128, 64), 256, 0, stream>>>(keys, kbf, DMODEL, ESIZE);
  k_transpose<<<dim3(128, 64), 256, 0, stream>>>(values, vbf, ESIZE, DMODEL);
  k_router<<<256, 256, 0, stream>>>(x, selT, idx4, g4);
  k_bucket<<<64, 256, 0, stream>>>(idx4, g4, btok, bgate, cnt);
  k_expert<<<dim3(128, 64), 256, 0, stream>>>(xbf, kbf, vbf, btok, bgate, cnt, out);
}

// Round 2
// 416.275 us; speedup vs baseline: 1.9573x; 1.9573x over previous
//
#include <hip/hip_runtime.h>

typedef __bf16 bf16x8 __attribute__((ext_vector_type(8)));
typedef float f32x4 __attribute__((ext_vector_type(4)));

#define N_TOK 8192
#define DMODEL 1024
#define NEXP 64
#define ESIZE 128
#define WL_MAX 576   // sum ceil(ck/64) <= 32768/64 + 64 = 576

__device__ __forceinline__ unsigned short f2bf(float f) {
  unsigned int u = __builtin_bit_cast(unsigned int, f);
  u += 0x7FFFu + ((u >> 16) & 1u);
  return (unsigned short)(u >> 16);
}

// K0: expert_sel [64][1024] -> selT [1024][64] fp32
__global__ void k_selT(const float* __restrict__ in, float* __restrict__ outT) {
  int id = blockIdx.x * 256 + threadIdx.x;
  int e = id & 63, j = id >> 6;
  outT[id] = in[e * DMODEL + j];
}

// K1: x fp32 -> bf16
__global__ void k_castx(const float* __restrict__ in, unsigned short* __restrict__ out) {
  size_t i = (size_t)(blockIdx.x * 256 + threadIdx.x) * 8;
  float4 a = *reinterpret_cast<const float4*>(in + i);
  float4 b = *reinterpret_cast<const float4*>(in + i + 4);
  uint4 o;
  o.x = f2bf(a.x) | ((unsigned)f2bf(a.y) << 16);
  o.y = f2bf(a.z) | ((unsigned)f2bf(a.w) << 16);
  o.z = f2bf(b.x) | ((unsigned)f2bf(b.y) << 16);
  o.w = f2bf(b.z) | ((unsigned)f2bf(b.w) << 16);
  *reinterpret_cast<uint4*>(out + i) = o;
}

// K2: per-expert transpose+cast: in [B][R][C] f32 -> out [B][C][R] bf16
__global__ void k_transpose(const float* __restrict__ in, unsigned short* __restrict__ out,
                            int R, int C) {
  __shared__ float t[32][33];
  int b = blockIdx.y;
  int tilesC = C >> 5;
  int tr = blockIdx.x / tilesC, tc = blockIdx.x % tilesC;
  int lr = threadIdx.x >> 5, lc = threadIdx.x & 31;
  const float* ip = in + (size_t)b * R * C;
  unsigned short* op = out + (size_t)b * R * C;
#pragma unroll
  for (int p = 0; p < 4; ++p)
    t[p * 8 + lr][lc] = ip[(size_t)(tr * 32 + p * 8 + lr) * C + tc * 32 + lc];
  __syncthreads();
#pragma unroll
  for (int p = 0; p < 4; ++p)
    op[(size_t)(tc * 32 + p * 8 + lr) * R + tr * 32 + lc] = f2bf(t[lc][p * 8 + lr]);
}

// K3: router — fp64 accumulation for top-k rank fidelity; wave handles 8 tokens.
__global__ __launch_bounds__(256) void k_router(const float* __restrict__ x,
                                                const float* __restrict__ selT,
                                                int4* __restrict__ idx4,
                                                float4* __restrict__ g4) {
  int lane = threadIdx.x & 63;
  int wid = blockIdx.x * 4 + (threadIdx.x >> 6);
  int tok0 = wid * 8;
  double acc[8];
#pragma unroll
  for (int t = 0; t < 8; ++t) acc[t] = 0.0;
  for (int j = 0; j < DMODEL; ++j) {
    double s = (double)selT[j * 64 + lane];
#pragma unroll
    for (int t = 0; t < 8; ++t)
      acc[t] += (double)x[(size_t)(tok0 + t) * DMODEL + j] * s;
  }
#pragma unroll
  for (int t = 0; t < 8; ++t) {
    double v = acc[t];
    int bi[4];
    double bl[4];
#pragma unroll
    for (int h = 0; h < 4; ++h) {
      double mv = v;
      int mi = lane;
#pragma unroll
      for (int off = 32; off > 0; off >>= 1) {
        double ov = __shfl_xor(mv, off);
        int oi = __shfl_xor(mi, off);
        if (ov > mv || (ov == mv && oi < mi)) { mv = ov; mi = oi; }
      }
      bi[h] = mi;
      bl[h] = mv;
      if (lane == mi) v = -1.0e300;
    }
    if (lane == 0) {
      idx4[tok0 + t] = make_int4(bi[0], bi[1], bi[2], bi[3]);
      float4 g;
      g.x = 1.0f / (1.0f + __expf(-(float)bl[0]));
      g.y = 1.0f / (1.0f + __expf(-(float)bl[1]));
      g.z = 1.0f / (1.0f + __expf(-(float)bl[2]));
      g.w = 1.0f / (1.0f + __expf(-(float)bl[3]));
      g4[tok0 + t] = g;
    }
  }
}

// K4: bucketize. btok entry = h*N_TOK + n  (== partial-row index; token = entry & 8191)
__global__ __launch_bounds__(256) void k_bucket(const int4* __restrict__ idx4,
                                                const float4* __restrict__ g4,
                                                int* __restrict__ btok,
                                                float* __restrict__ bgate,
                                                int* __restrict__ cnt) {
  int e = blockIdx.x;
  int tid = threadIdx.x, lane = tid & 63, wid = tid >> 6;
  __shared__ int wcnt[4];
  int base = 0;
  for (int chunk = 0; chunk < N_TOK; chunk += 256) {
    int n = chunk + tid;
    int4 I = idx4[n];
    float4 G = g4[n];
    int h = (I.x == e) ? 0 : (I.y == e) ? 1 : (I.z == e) ? 2 : (I.w == e) ? 3 : -1;
    unsigned long long b = __ballot(h >= 0);
    if (lane == 0) wcnt[wid] = (int)__popcll(b);
    __syncthreads();
    int wbase = base;
    for (int w = 0; w < wid; ++w) wbase += wcnt[w];
    if (h >= 0) {
      int pos = wbase + (int)__popcll(b & ((1ULL << lane) - 1ULL));
      btok[e * N_TOK + pos] = h * N_TOK + n;
      bgate[e * N_TOK + pos] = (h == 0) ? G.x : (h == 1) ? G.y : (h == 2) ? G.z : G.w;
    }
    base += wcnt[0] + wcnt[1] + wcnt[2] + wcnt[3];
    __syncthreads();
  }
  if (tid == 0) cnt[e] = base;
}

// K5: compact worklist of (expert, tile) pairs. 1 block, 64 threads.
__global__ void k_worklist(const int* __restrict__ cnt, int* __restrict__ wl) {
  int lane = threadIdx.x;
  int nt = (cnt[lane] + 63) >> 6;
  int off = nt;
  for (int d = 1; d < 64; d <<= 1) {
    int o = __shfl_up(off, d);
    if (lane >= d) off += o;
  }
  int total = __shfl(off, 63);
  off -= nt;
  for (int t = 0; t < nt; ++t) wl[off + t] = (lane << 7) | t;
  for (int i = total + lane; i < WL_MAX; i += 64) wl[i] = -1;
}

// K6: fused per-(expert,tile): S = relu(X Kt)*gate (MFMA, direct-global frags),
//     then part[row] = S @ V (MFMA, direct-global frags), non-atomic stores.
__global__ __launch_bounds__(256, 3) void k_expert(
    const unsigned short* __restrict__ xbf, const unsigned short* __restrict__ kbf,
    const unsigned short* __restrict__ vbf, const int* __restrict__ wl,
    const int* __restrict__ btok, const float* __restrict__ bgate,
    const int* __restrict__ cnt, float* __restrict__ part) {
  // XCD-chunked swizzle: 8 consecutive worklist entries per XCD chunk
  int wid = (blockIdx.x & 7) * (WL_MAX / 8) + (blockIdx.x >> 3);
  int wle = wl[wid];
  if (wle < 0) return;
  int k = wle >> 7, tile = wle & 127;
  int ck = cnt[k];
  int tid = threadIdx.x, lane = tid & 63;
  int wv = tid >> 6, wr = wv >> 1, wc = wv & 1;
  int col = lane & 15, grp = lane >> 4;

  __shared__ unsigned short lS[64][136];  // scores tok x e (272B stride: conflict-benign)
  __shared__ int sRow[64];
  __shared__ float sGate[64];

  if (tid < 64) {
    int i = tile * 64 + tid;
    bool valid = i < ck;
    sRow[tid] = valid ? btok[k * N_TOK + i] : 4 * N_TOK;  // dump row if invalid
    sGate[tid] = valid ? bgate[k * N_TOK + i] : 0.0f;
  }
  __syncthreads();

  const unsigned short* kb = kbf + (size_t)k * (ESIZE * DMODEL);
  const unsigned short* vb = vbf + (size_t)k * (DMODEL * ESIZE);

  // ---- GEMM1: wave (wr,wc) -> tokens [wr*32,+32), e-cols [wc*64,+64)
  const unsigned short* aP[2];
  const unsigned short* bP[4];
#pragma unroll
  for (int mf = 0; mf < 2; ++mf)
    aP[mf] = xbf + (size_t)(sRow[wr * 32 + mf * 16 + col] & (N_TOK - 1)) * DMODEL + grp * 8;
#pragma unroll
  for (int nf = 0; nf < 4; ++nf)
    bP[nf] = kb + (size_t)(wc * 64 + nf * 16 + col) * DMODEL + grp * 8;

  f32x4 acc[2][4] = {};
#pragma unroll 4
  for (int kk = 0; kk < DMODEL; kk += 32) {
    bf16x8 aF[2], bF[4];
#pragma unroll
    for (int mf = 0; mf < 2; ++mf)
      aF[mf] = *reinterpret_cast<const bf16x8*>(aP[mf] + kk);
#pragma unroll
    for (int nf = 0; nf < 4; ++nf)
      bF[nf] = *reinterpret_cast<const bf16x8*>(bP[nf] + kk);
#pragma unroll
    for (int mf = 0; mf < 2; ++mf)
#pragma unroll
      for (int nf = 0; nf < 4; ++nf)
        acc[mf][nf] = __builtin_amdgcn_mfma_f32_16x16x32_bf16(aF[mf], bF[nf], acc[mf][nf], 0, 0, 0);
  }

  // relu*gate -> lS (bf16)
#pragma unroll
  for (int mf = 0; mf < 2; ++mf) {
    int trow = wr * 32 + mf * 16 + grp * 4;
#pragma unroll
    for (int nf = 0; nf < 4; ++nf) {
      int e = wc * 64 + nf * 16 + col;
#pragma unroll
      for (int r = 0; r < 4; ++r) {
        float s = acc[mf][nf][r];
        s = s > 0.0f ? s * sGate[trow + r] : 0.0f;
        lS[trow + r][e] = f2bf(s);
      }
    }
  }
  __syncthreads();

  // ---- GEMM2: wave (wr,wc) -> tokens [wr*32,+32), v-cols {ch*64 + wc*32 + [0,32)}
  bf16x8 aS[2][4];
#pragma unroll
  for (int mf = 0; mf < 2; ++mf)
#pragma unroll
    for (int kc = 0; kc < 4; ++kc)
      aS[mf][kc] = *reinterpret_cast<const bf16x8*>(&lS[wr * 32 + mf * 16 + col][kc * 32 + grp * 8]);

  float* rowPtr[2][4];
#pragma unroll
  for (int mf = 0; mf < 2; ++mf)
#pragma unroll
    for (int r = 0; r < 4; ++r)
      rowPtr[mf][r] = part + (size_t)sRow[wr * 32 + mf * 16 + grp * 4 + r] * DMODEL + wc * 32 + col;

  const unsigned short* vB[2];
#pragma unroll
  for (int nf = 0; nf < 2; ++nf)
    vB[nf] = vb + (size_t)(wc * 32 + nf * 16 + col) * ESIZE + grp * 8;

#pragma unroll 2
  for (int ch = 0; ch < 16; ++ch) {
    f32x4 a2[2][2] = {};
#pragma unroll
    for (int kc = 0; kc < 4; ++kc) {
      bf16x8 b0 = *reinterpret_cast<const bf16x8*>(vB[0] + (size_t)ch * 64 * ESIZE + kc * 32);
      bf16x8 b1 = *reinterpret_cast<const bf16x8*>(vB[1] + (size_t)ch * 64 * ESIZE + kc * 32);
#pragma unroll
      for (int mf = 0; mf < 2; ++mf) {
        a2[mf][0] = __builtin_amdgcn_mfma_f32_16x16x32_bf16(aS[mf][kc], b0, a2[mf][0], 0, 0, 0);
        a2[mf][1] = __builtin_amdgcn_mfma_f32_16x16x32_bf16(aS[mf][kc], b1, a2[mf][1], 0, 0, 0);
      }
    }
#pragma unroll
    for (int mf = 0; mf < 2; ++mf)
#pragma unroll
      for (int nf = 0; nf < 2; ++nf)
#pragma unroll
        for (int r = 0; r < 4; ++r)
          rowPtr[mf][r][ch * 64 + nf * 16] = a2[mf][nf][r];
  }
}

// K7: out[n][v] = sum_h part[h*N_TOK+n][v]  (fully overwrites d_out, no memset needed)
__global__ void k_sum(const float* __restrict__ part, float* __restrict__ out) {
  size_t i = ((size_t)blockIdx.x * 256 + threadIdx.x) * 4;
  const size_t stride = (size_t)N_TOK * DMODEL;
  float4 a = *reinterpret_cast<const float4*>(part + i);
  float4 b = *reinterpret_cast<const float4*>(part + stride + i);
  float4 c = *reinterpret_cast<const float4*>(part + 2 * stride + i);
  float4 d = *reinterpret_cast<const float4*>(part + 3 * stride + i);
  float4 o;
  o.x = a.x + b.x + c.x + d.x;
  o.y = a.y + b.y + c.y + d.y;
  o.z = a.z + b.z + c.z + d.z;
  o.w = a.w + b.w + c.w + d.w;
  *reinterpret_cast<float4*>(out + i) = o;
}

extern "C" void kernel_launch(void* const* d_in, const int* in_sizes, int n_in,
                              void* d_out, int out_size, void* d_ws, size_t ws_size,
                              hipStream_t stream) {
  const float* x = (const float*)d_in[0];
  const float* esel = (const float*)d_in[1];
  const float* keys = (const float*)d_in[2];
  const float* values = (const float*)d_in[3];
  float* out = (float*)d_out;

  char* p = (char*)d_ws;
  unsigned short* xbf = (unsigned short*)p; p += (size_t)N_TOK * DMODEL * 2;
  unsigned short* kbf = (unsigned short*)p; p += (size_t)NEXP * DMODEL * ESIZE * 2;
  unsigned short* vbf = (unsigned short*)p; p += (size_t)NEXP * DMODEL * ESIZE * 2;
  float* selT = (float*)p; p += (size_t)DMODEL * NEXP * 4;
  float4* g4 = (float4*)p; p += (size_t)N_TOK * 16;
  int4* idx4 = (int4*)p; p += (size_t)N_TOK * 16;
  int* btok = (int*)p; p += (size_t)NEXP * N_TOK * 4;
  float* bgate = (float*)p; p += (size_t)NEXP * N_TOK * 4;
  float* part = (float*)p; p += ((size_t)4 * N_TOK + 1) * DMODEL * 4;  // +1 dump row
  int* cnt = (int*)p; p += 256;
  int* wl = (int*)p; p += WL_MAX * 4;
  (void)ws_size; (void)in_sizes; (void)n_in;

  k_selT<<<256, 256, 0, stream>>>(esel, selT);
  k_castx<<<(N_TOK * DMODEL / 8) / 256, 256, 0, stream>>>(x, xbf);
  k_transpose<<<dim3(128, 64), 256, 0, stream>>>(keys, kbf, DMODEL, ESIZE);
  k_transpose<<<dim3(128, 64), 256, 0, stream>>>(values, vbf, ESIZE, DMODEL);
  k_router<<<256, 256, 0, stream>>>(x, selT, idx4, g4);
  k_bucket<<<64, 256, 0, stream>>>(idx4, g4, btok, bgate, cnt);
  k_worklist<<<1, 64, 0, stream>>>(cnt, wl);
  k_expert<<<WL_MAX, 256, 0, stream>>>(xbf, kbf, vbf, wl, btok, bgate, cnt, part);
  k_sum<<<(N_TOK * DMODEL / 4) / 256, 256, 0, stream>>>(part, out);
}

// Round 3
// 263.251 us; speedup vs baseline: 3.0951x; 1.5813x over previous
//
#include <hip/hip_runtime.h>

typedef __bf16 bf16x8 __attribute__((ext_vector_type(8)));
typedef float f32x4 __attribute__((ext_vector_type(4)));

#define N_TOK 8192
#define DMODEL 1024
#define NEXP 64
#define ESIZE 128
#define WL_MAX 576   // sum ceil(ck/64) <= 32768/64 + 64 = 576

__device__ __forceinline__ unsigned short f2bf(float f) {
  unsigned int u = __builtin_bit_cast(unsigned int, f);
  u += 0x7FFFu + ((u >> 16) & 1u);
  return (unsigned short)(u >> 16);
}

__device__ __forceinline__ float b2f(unsigned short u) {
  unsigned int v = ((unsigned int)u) << 16;
  return __builtin_bit_cast(float, v);
}

// K0: expert_sel [64][1024] -> selT [1024][64] fp32
__global__ void k_selT(const float* __restrict__ in, float* __restrict__ outT) {
  int id = blockIdx.x * 256 + threadIdx.x;
  int e = id & 63, j = id >> 6;
  outT[id] = in[e * DMODEL + j];
}

// K1: x fp32 -> bf16
__global__ void k_castx(const float* __restrict__ in, unsigned short* __restrict__ out) {
  size_t i = (size_t)(blockIdx.x * 256 + threadIdx.x) * 8;
  float4 a = *reinterpret_cast<const float4*>(in + i);
  float4 b = *reinterpret_cast<const float4*>(in + i + 4);
  uint4 o;
  o.x = f2bf(a.x) | ((unsigned)f2bf(a.y) << 16);
  o.y = f2bf(a.z) | ((unsigned)f2bf(a.w) << 16);
  o.z = f2bf(b.x) | ((unsigned)f2bf(b.y) << 16);
  o.w = f2bf(b.z) | ((unsigned)f2bf(b.w) << 16);
  *reinterpret_cast<uint4*>(out + i) = o;
}

// K2: per-expert transpose+cast: in [B][R][C] f32 -> out [B][C][R] bf16
__global__ void k_transpose(const float* __restrict__ in, unsigned short* __restrict__ out,
                            int R, int C) {
  __shared__ float t[32][33];
  int b = blockIdx.y;
  int tilesC = C >> 5;
  int tr = blockIdx.x / tilesC, tc = blockIdx.x % tilesC;
  int lr = threadIdx.x >> 5, lc = threadIdx.x & 31;
  const float* ip = in + (size_t)b * R * C;
  unsigned short* op = out + (size_t)b * R * C;
#pragma unroll
  for (int p = 0; p < 4; ++p)
    t[p * 8 + lr][lc] = ip[(size_t)(tr * 32 + p * 8 + lr) * C + tc * 32 + lc];
  __syncthreads();
#pragma unroll
  for (int p = 0; p < 4; ++p)
    op[(size_t)(tc * 32 + p * 8 + lr) * R + tr * 32 + lc] = f2bf(t[lc][p * 8 + lr]);
}

// K3: router — LDS-tiled fp64-accum GEMM (rank fidelity) + per-token top-4.
// Block: 32 tokens, 256 threads. Thread tile: 2 tokens x 4 experts.
__global__ __launch_bounds__(256) void k_router(const float* __restrict__ x,
                                                const float* __restrict__ selT,
                                                int4* __restrict__ idx4,
                                                float4* __restrict__ g4) {
  int tid = threadIdx.x;
  int tok0 = blockIdx.x * 32;
  int ty = tid >> 4, tx = tid & 15;          // ty: token pair, tx: expert quad
  __shared__ float lx[32][34];               // [d][tok], stride 34 (8B-aligned float2)
  __shared__ float ls[32][64];               // [d][exp]
  __shared__ double lg[32][65];              // logits [tok][exp]

  int tokr = tid >> 3, dseg = (tid & 7) * 4; // x staging map
  int srow = tid >> 3, scol = (tid & 7) * 8; // sel staging map

  double acc[2][4];
#pragma unroll
  for (int r = 0; r < 2; ++r)
#pragma unroll
    for (int c = 0; c < 4; ++c) acc[r][c] = 0.0;

  for (int cc = 0; cc < DMODEL; cc += 32) {
    float4 xv = *reinterpret_cast<const float4*>(&x[(size_t)(tok0 + tokr) * DMODEL + cc + dseg]);
    lx[dseg + 0][tokr] = xv.x;
    lx[dseg + 1][tokr] = xv.y;
    lx[dseg + 2][tokr] = xv.z;
    lx[dseg + 3][tokr] = xv.w;
    *reinterpret_cast<float4*>(&ls[srow][scol]) =
        *reinterpret_cast<const float4*>(&selT[(size_t)(cc + srow) * 64 + scol]);
    *reinterpret_cast<float4*>(&ls[srow][scol + 4]) =
        *reinterpret_cast<const float4*>(&selT[(size_t)(cc + srow) * 64 + scol + 4]);
    __syncthreads();
#pragma unroll
    for (int j = 0; j < 32; ++j) {
      float2 xj = *reinterpret_cast<const float2*>(&lx[j][ty * 2]);
      float4 sj = *reinterpret_cast<const float4*>(&ls[j][tx * 4]);
      double x0 = (double)xj.x, x1 = (double)xj.y;
      double s0 = (double)sj.x, s1 = (double)sj.y, s2 = (double)sj.z, s3 = (double)sj.w;
      acc[0][0] += x0 * s0; acc[0][1] += x0 * s1; acc[0][2] += x0 * s2; acc[0][3] += x0 * s3;
      acc[1][0] += x1 * s0; acc[1][1] += x1 * s1; acc[1][2] += x1 * s2; acc[1][3] += x1 * s3;
    }
    __syncthreads();
  }

#pragma unroll
  for (int r = 0; r < 2; ++r)
#pragma unroll
    for (int c = 0; c < 4; ++c) lg[ty * 2 + r][tx * 4 + c] = acc[r][c];
  __syncthreads();

  if (tid < 32) {
    double bv0 = -1.0e300, bv1 = -1.0e300, bv2 = -1.0e300, bv3 = -1.0e300;
    int bi0 = 0, bi1 = 0, bi2 = 0, bi3 = 0;
    for (int e = 0; e < 64; ++e) {
      double v = lg[tid][e];
      if (v > bv3) {
        if (v > bv0) {
          bv3 = bv2; bi3 = bi2; bv2 = bv1; bi2 = bi1; bv1 = bv0; bi1 = bi0; bv0 = v; bi0 = e;
        } else if (v > bv1) {
          bv3 = bv2; bi3 = bi2; bv2 = bv1; bi2 = bi1; bv1 = v; bi1 = e;
        } else if (v > bv2) {
          bv3 = bv2; bi3 = bi2; bv2 = v; bi2 = e;
        } else {
          bv3 = v; bi3 = e;
        }
      }
    }
    idx4[tok0 + tid] = make_int4(bi0, bi1, bi2, bi3);
    float4 g;
    g.x = 1.0f / (1.0f + __expf(-(float)bv0));
    g.y = 1.0f / (1.0f + __expf(-(float)bv1));
    g.z = 1.0f / (1.0f + __expf(-(float)bv2));
    g.w = 1.0f / (1.0f + __expf(-(float)bv3));
    g4[tok0 + tid] = g;
  }
}

// K4: bucketize. btok entry = h*N_TOK + n  (== partial-row index; token = entry & 8191)
__global__ __launch_bounds__(256) void k_bucket(const int4* __restrict__ idx4,
                                                const float4* __restrict__ g4,
                                                int* __restrict__ btok,
                                                float* __restrict__ bgate,
                                                int* __restrict__ cnt) {
  int e = blockIdx.x;
  int tid = threadIdx.x, lane = tid & 63, wid = tid >> 6;
  __shared__ int wcnt[4];
  int base = 0;
  for (int chunk = 0; chunk < N_TOK; chunk += 256) {
    int n = chunk + tid;
    int4 I = idx4[n];
    float4 G = g4[n];
    int h = (I.x == e) ? 0 : (I.y == e) ? 1 : (I.z == e) ? 2 : (I.w == e) ? 3 : -1;
    unsigned long long b = __ballot(h >= 0);
    if (lane == 0) wcnt[wid] = (int)__popcll(b);
    __syncthreads();
    int wbase = base;
    for (int w = 0; w < wid; ++w) wbase += wcnt[w];
    if (h >= 0) {
      int pos = wbase + (int)__popcll(b & ((1ULL << lane) - 1ULL));
      btok[e * N_TOK + pos] = h * N_TOK + n;
      bgate[e * N_TOK + pos] = (h == 0) ? G.x : (h == 1) ? G.y : (h == 2) ? G.z : G.w;
    }
    base += wcnt[0] + wcnt[1] + wcnt[2] + wcnt[3];
    __syncthreads();
  }
  if (tid == 0) cnt[e] = base;
}

// K5: compact worklist of (expert, tile) pairs. 1 block, 64 threads.
__global__ void k_worklist(const int* __restrict__ cnt, int* __restrict__ wl) {
  int lane = threadIdx.x;
  int nt = (cnt[lane] + 63) >> 6;
  int off = nt;
  for (int d = 1; d < 64; d <<= 1) {
    int o = __shfl_up(off, d);
    if (lane >= d) off += o;
  }
  int total = __shfl(off, 63);
  off -= nt;
  for (int t = 0; t < nt; ++t) wl[off + t] = (lane << 7) | t;
  for (int i = total + lane; i < WL_MAX; i += 64) wl[i] = -1;
}

// K6: fused per-(expert,tile): S = relu(X Kt)*gate (MFMA, direct-global frags),
//     then part[row] = S @ V (MFMA, direct-global frags), bf16 non-atomic stores.
__global__ __launch_bounds__(256, 3) void k_expert(
    const unsigned short* __restrict__ xbf, const unsigned short* __restrict__ kbf,
    const unsigned short* __restrict__ vbf, const int* __restrict__ wl,
    const int* __restrict__ btok, const float* __restrict__ bgate,
    const int* __restrict__ cnt, unsigned short* __restrict__ part) {
  // XCD-chunked swizzle: contiguous worklist chunk per XCD (576 % 8 == 0)
  int wid = (blockIdx.x & 7) * (WL_MAX / 8) + (blockIdx.x >> 3);
  int wle = wl[wid];
  if (wle < 0) return;
  int k = wle >> 7, tile = wle & 127;
  int ck = cnt[k];
  int tid = threadIdx.x, lane = tid & 63;
  int wv = tid >> 6, wr = wv >> 1, wc = wv & 1;
  int col = lane & 15, grp = lane >> 4;

  __shared__ unsigned short lS[64][136];  // scores tok x e
  __shared__ int sRow[64];
  __shared__ float sGate[64];

  if (tid < 64) {
    int i = tile * 64 + tid;
    bool valid = i < ck;
    sRow[tid] = valid ? btok[k * N_TOK + i] : 4 * N_TOK;  // dump row if invalid
    sGate[tid] = valid ? bgate[k * N_TOK + i] : 0.0f;
  }
  __syncthreads();

  const unsigned short* kb = kbf + (size_t)k * (ESIZE * DMODEL);
  const unsigned short* vb = vbf + (size_t)k * (DMODEL * ESIZE);

  // ---- GEMM1: wave (wr,wc) -> tokens [wr*32,+32), e-cols [wc*64,+64)
  const unsigned short* aP[2];
  const unsigned short* bP[4];
#pragma unroll
  for (int mf = 0; mf < 2; ++mf)
    aP[mf] = xbf + (size_t)(sRow[wr * 32 + mf * 16 + col] & (N_TOK - 1)) * DMODEL + grp * 8;
#pragma unroll
  for (int nf = 0; nf < 4; ++nf)
    bP[nf] = kb + (size_t)(wc * 64 + nf * 16 + col) * DMODEL + grp * 8;

  f32x4 acc[2][4] = {};
#pragma unroll 4
  for (int kk = 0; kk < DMODEL; kk += 32) {
    bf16x8 aF[2], bF[4];
#pragma unroll
    for (int mf = 0; mf < 2; ++mf)
      aF[mf] = *reinterpret_cast<const bf16x8*>(aP[mf] + kk);
#pragma unroll
    for (int nf = 0; nf < 4; ++nf)
      bF[nf] = *reinterpret_cast<const bf16x8*>(bP[nf] + kk);
#pragma unroll
    for (int mf = 0; mf < 2; ++mf)
#pragma unroll
      for (int nf = 0; nf < 4; ++nf)
        acc[mf][nf] = __builtin_amdgcn_mfma_f32_16x16x32_bf16(aF[mf], bF[nf], acc[mf][nf], 0, 0, 0);
  }

  // relu*gate -> lS (bf16)
#pragma unroll
  for (int mf = 0; mf < 2; ++mf) {
    int trow = wr * 32 + mf * 16 + grp * 4;
#pragma unroll
    for (int nf = 0; nf < 4; ++nf) {
      int e = wc * 64 + nf * 16 + col;
#pragma unroll
      for (int r = 0; r < 4; ++r) {
        float s = acc[mf][nf][r];
        s = s > 0.0f ? s * sGate[trow + r] : 0.0f;
        lS[trow + r][e] = f2bf(s);
      }
    }
  }
  __syncthreads();

  // ---- GEMM2: wave (wr,wc) -> tokens [wr*32,+32), v-cols {ch*64 + wc*32 + [0,32)}
  bf16x8 aS[2][4];
#pragma unroll
  for (int mf = 0; mf < 2; ++mf)
#pragma unroll
    for (int kc = 0; kc < 4; ++kc)
      aS[mf][kc] = *reinterpret_cast<const bf16x8*>(&lS[wr * 32 + mf * 16 + col][kc * 32 + grp * 8]);

  unsigned short* rowPtr[2][4];
#pragma unroll
  for (int mf = 0; mf < 2; ++mf)
#pragma unroll
    for (int r = 0; r < 4; ++r)
      rowPtr[mf][r] = part + (size_t)sRow[wr * 32 + mf * 16 + grp * 4 + r] * DMODEL + wc * 32 + col;

  const unsigned short* vB[2];
#pragma unroll
  for (int nf = 0; nf < 2; ++nf)
    vB[nf] = vb + (size_t)(wc * 32 + nf * 16 + col) * ESIZE + grp * 8;

#pragma unroll 2
  for (int ch = 0; ch < 16; ++ch) {
    f32x4 a2[2][2] = {};
#pragma unroll
    for (int kc = 0; kc < 4; ++kc) {
      bf16x8 b0 = *reinterpret_cast<const bf16x8*>(vB[0] + (size_t)ch * 64 * ESIZE + kc * 32);
      bf16x8 b1 = *reinterpret_cast<const bf16x8*>(vB[1] + (size_t)ch * 64 * ESIZE + kc * 32);
#pragma unroll
      for (int mf = 0; mf < 2; ++mf) {
        a2[mf][0] = __builtin_amdgcn_mfma_f32_16x16x32_bf16(aS[mf][kc], b0, a2[mf][0], 0, 0, 0);
        a2[mf][1] = __builtin_amdgcn_mfma_f32_16x16x32_bf16(aS[mf][kc], b1, a2[mf][1], 0, 0, 0);
      }
    }
#pragma unroll
    for (int mf = 0; mf < 2; ++mf)
#pragma unroll
      for (int nf = 0; nf < 2; ++nf)
#pragma unroll
        for (int r = 0; r < 4; ++r)
          rowPtr[mf][r][ch * 64 + nf * 16] = f2bf(a2[mf][nf][r]);
  }
}

// K7: out[n][v] = sum_h part[h*N_TOK+n][v]  (bf16 partials -> fp32 out, full overwrite)
__global__ void k_sum(const unsigned short* __restrict__ part, float* __restrict__ out) {
  size_t i = ((size_t)blockIdx.x * 256 + threadIdx.x) * 8;
  const size_t stride = (size_t)N_TOK * DMODEL;
  uint4 a = *reinterpret_cast<const uint4*>(part + i);
  uint4 b = *reinterpret_cast<const uint4*>(part + stride + i);
  uint4 c = *reinterpret_cast<const uint4*>(part + 2 * stride + i);
  uint4 d = *reinterpret_cast<const uint4*>(part + 3 * stride + i);
  float o[8];
#pragma unroll
  for (int q = 0; q < 4; ++q) {
    unsigned ua = (&a.x)[q], ub = (&b.x)[q], uc = (&c.x)[q], ud = (&d.x)[q];
    o[q * 2 + 0] = b2f((unsigned short)ua) + b2f((unsigned short)ub) +
                   b2f((unsigned short)uc) + b2f((unsigned short)ud);
    o[q * 2 + 1] = b2f((unsigned short)(ua >> 16)) + b2f((unsigned short)(ub >> 16)) +
                   b2f((unsigned short)(uc >> 16)) + b2f((unsigned short)(ud >> 16));
  }
  *reinterpret_cast<float4*>(out + i) = make_float4(o[0], o[1], o[2], o[3]);
  *reinterpret_cast<float4*>(out + i + 4) = make_float4(o[4], o[5], o[6], o[7]);
}

extern "C" void kernel_launch(void* const* d_in, const int* in_sizes, int n_in,
                              void* d_out, int out_size, void* d_ws, size_t ws_size,
                              hipStream_t stream) {
  const float* x = (const float*)d_in[0];
  const float* esel = (const float*)d_in[1];
  const float* keys = (const float*)d_in[2];
  const float* values = (const float*)d_in[3];
  float* out = (float*)d_out;

  char* p = (char*)d_ws;
  unsigned short* xbf = (unsigned short*)p; p += (size_t)N_TOK * DMODEL * 2;
  unsigned short* kbf = (unsigned short*)p; p += (size_t)NEXP * DMODEL * ESIZE * 2;
  unsigned short* vbf = (unsigned short*)p; p += (size_t)NEXP * DMODEL * ESIZE * 2;
  float* selT = (float*)p; p += (size_t)DMODEL * NEXP * 4;
  float4* g4 = (float4*)p; p += (size_t)N_TOK * 16;
  int4* idx4 = (int4*)p; p += (size_t)N_TOK * 16;
  int* btok = (int*)p; p += (size_t)NEXP * N_TOK * 4;
  float* bgate = (float*)p; p += (size_t)NEXP * N_TOK * 4;
  unsigned short* part = (unsigned short*)p; p += ((size_t)4 * N_TOK + 1) * DMODEL * 2;  // +1 dump row
  int* cnt = (int*)p; p += 256;
  int* wl = (int*)p; p += WL_MAX * 4;
  (void)ws_size; (void)in_sizes; (void)n_in;

  k_selT<<<256, 256, 0, stream>>>(esel, selT);
  k_castx<<<(N_TOK * DMODEL / 8) / 256, 256, 0, stream>>>(x, xbf);
  k_transpose<<<dim3(128, 64), 256, 0, stream>>>(keys, kbf, DMODEL, ESIZE);
  k_transpose<<<dim3(128, 64), 256, 0, stream>>>(values, vbf, ESIZE, DMODEL);
  k_router<<<256, 256, 0, stream>>>(x, selT, idx4, g4);
  k_bucket<<<64, 256, 0, stream>>>(idx4, g4, btok, bgate, cnt);
  k_worklist<<<1, 64, 0, stream>>>(cnt, wl);
  k_expert<<<WL_MAX, 256, 0, stream>>>(xbf, kbf, vbf, wl, btok, bgate, cnt, part);
  k_sum<<<(N_TOK * DMODEL / 8) / 256, 256, 0, stream>>>(part, out);
}